// Round 6
// baseline (410.928 us; speedup 1.0000x reference)
//
#include <hip/hip_runtime.h>

#define D_IN 128
#define HID 256
#define BKT_SHIFT 9
#define BKT_SIZE 512     // nodes per bucket (N<=65536 -> nbkt<=128)
#define CHUNK 8192       // edges per block in binning kernels

typedef __attribute__((ext_vector_type(8))) short short8;   // 8 bf16 MFMA A/B frag
typedef __attribute__((ext_vector_type(4))) float floatx4;  // MFMA C/D frag

// fp32 -> bf16 (RNE), branch-free; inputs finite
static __device__ __forceinline__ unsigned short f2b(float f) {
  unsigned u = __float_as_uint(f);
  unsigned r = (u + 0x7fffu + ((u >> 16) & 1u)) >> 16;
  return (unsigned short)r;
}

static __device__ __forceinline__ void unpack8(uint4 v, float* f) {
  f[0] = __uint_as_float(v.x << 16); f[1] = __uint_as_float(v.x & 0xffff0000u);
  f[2] = __uint_as_float(v.y << 16); f[3] = __uint_as_float(v.y & 0xffff0000u);
  f[4] = __uint_as_float(v.z << 16); f[5] = __uint_as_float(v.z & 0xffff0000u);
  f[6] = __uint_as_float(v.w << 16); f[7] = __uint_as_float(v.w & 0xffff0000u);
}

static __device__ __forceinline__ void acc_fma(float* acc, uint4 v, float w) {
  float g[8];
  unpack8(v, g);
#pragma unroll
  for (int d = 0; d < 8; ++d) acc[d] = fmaf(g[d], w, acc[d]);
}

// ================= CSR build =================

// fused: per-node degree (global atomics, L2-resident cnt) + per-bucket histogram
__global__ __launch_bounds__(256) void cdh_kernel(const int* __restrict__ dst,
                                                  int* __restrict__ cnt,
                                                  int* __restrict__ bkt_cnt,
                                                  int E, int nbkt) {
  __shared__ int hist[128];
  const int tid = threadIdx.x;
  if (tid < nbkt) hist[tid] = 0;
  __syncthreads();
  const int base = blockIdx.x * CHUNK;
  const int end = min(base + CHUNK, E);
  for (int e = base + tid; e < end; e += 256) {
    int d = dst[e];
    atomicAdd(&cnt[d], 1);
    atomicAdd(&hist[d >> BKT_SHIFT], 1);
  }
  __syncthreads();
  if (tid < nbkt && hist[tid] > 0) atomicAdd(&bkt_cnt[tid], hist[tid]);
}

// scanA: padded row_start partial scan (rows padded to multiple of 8) + dinv
__global__ __launch_bounds__(256) void scanA_kernel(const int* __restrict__ cnt,
                                                    float* __restrict__ dinv,
                                                    int* __restrict__ row_start,
                                                    int* __restrict__ blksum, int n) {
  __shared__ int wsums[4];
  const int tid = threadIdx.x;
  const int base = blockIdx.x * 1024 + tid * 4;
  int v0 = 0, v1 = 0, v2 = 0, v3 = 0;
  if (base + 3 < n) {
    int4 v = *(const int4*)(cnt + base);
    v0 = v.x; v1 = v.y; v2 = v.z; v3 = v.w;
  } else {
    if (base < n)     v0 = cnt[base];
    if (base + 1 < n) v1 = cnt[base + 1];
    if (base + 2 < n) v2 = cnt[base + 2];
    if (base + 3 < n) v3 = cnt[base + 3];
  }
  if (base < n)     dinv[base]     = rsqrtf((float)(v0 + 1));
  if (base + 1 < n) dinv[base + 1] = rsqrtf((float)(v1 + 1));
  if (base + 2 < n) dinv[base + 2] = rsqrtf((float)(v2 + 1));
  if (base + 3 < n) dinv[base + 3] = rsqrtf((float)(v3 + 1));

  const int p0 = (v0 + 7) & ~7, p1 = (v1 + 7) & ~7, p2 = (v2 + 7) & ~7, p3 = (v3 + 7) & ~7;
  const int s = p0 + p1 + p2 + p3;
  const int lane = tid & 63, wid = tid >> 6;
  int incl = s;
#pragma unroll
  for (int off = 1; off < 64; off <<= 1) {
    int t = __shfl_up(incl, off);
    if (lane >= off) incl += t;
  }
  if (lane == 63) wsums[wid] = incl;
  __syncthreads();
  int wex = 0;
  for (int w = 0; w < wid; ++w) wex += wsums[w];
  const int texcl = wex + incl - s;
  if (base < n)     row_start[base]     = texcl;
  if (base + 1 < n) row_start[base + 1] = texcl + p0;
  if (base + 2 < n) row_start[base + 2] = texcl + p0 + p1;
  if (base + 3 < n) row_start[base + 3] = texcl + p0 + p1 + p2;
  if (tid == 255) blksum[blockIdx.x] = wex + incl;
}

// scan_mid: threads 0..127 scan bucket counts -> bkt_start/cursor; threads 128..191 scan blksum
__global__ __launch_bounds__(256) void scan_mid_kernel(const int* __restrict__ bkt_cnt,
                                                       int* __restrict__ bkt_start,
                                                       int* __restrict__ bkt_cursor,
                                                       int nbkt, int E,
                                                       int* __restrict__ blksum, int nb) {
  __shared__ int w0tot;
  const int tid = threadIdx.x;
  int incA = 0, vA = 0;
  if (tid < 128) {
    const int lane = tid & 63;
    vA = (tid < nbkt) ? bkt_cnt[tid] : 0;
    incA = vA;
#pragma unroll
    for (int off = 1; off < 64; off <<= 1) {
      int t = __shfl_up(incA, off);
      if (lane >= off) incA += t;
    }
    if (tid == 63) w0tot = incA;
  }
  __syncthreads();
  if (tid < 128) {
    int ex = incA - vA + ((tid >= 64) ? w0tot : 0);
    if (tid < nbkt) { bkt_start[tid] = ex; bkt_cursor[tid] = ex; }
    if (tid == 0) bkt_start[nbkt] = E;
  } else if (tid < 192) {
    const int lane = tid - 128;
    int v = (lane < nb) ? blksum[lane] : 0;
    int incl = v;
#pragma unroll
    for (int off = 1; off < 64; off <<= 1) {
      int t = __shfl_up(incl, off);
      if (lane >= off) incl += t;
    }
    if (lane < nb) blksum[lane] = incl - v;
    if (lane == 63) blksum[nb] = incl;
  }
}

// scanC: add block offsets; write row_start[n] (padded edge total)
__global__ __launch_bounds__(256) void scanC_kernel(int* __restrict__ row_start,
                                                    const int* __restrict__ blksum,
                                                    int n, int nb) {
  const int base = blockIdx.x * 1024 + threadIdx.x * 4;
  const int off = blksum[blockIdx.x];
  if (blockIdx.x > 0) {
#pragma unroll
    for (int j = 0; j < 4; ++j)
      if (base + j < n) row_start[base + j] += off;
  }
  if (blockIdx.x == 0 && threadIdx.x == 0) row_start[n] = blksum[nb];
}

// P1c: bin edges into bucket-contiguous runs of ebuf
__global__ __launch_bounds__(256) void bin_scatter_kernel(const int* __restrict__ src,
                                                          const int* __restrict__ dst,
                                                          int* __restrict__ bkt_cursor,
                                                          int2* __restrict__ ebuf,
                                                          int E, int nbkt) {
  __shared__ int hist[128];
  __shared__ int bbase[128];
  const int tid = threadIdx.x;
  if (tid < nbkt) hist[tid] = 0;
  __syncthreads();
  const int base = blockIdx.x * CHUNK;
  const int end = min(base + CHUNK, E);
  for (int e = base + tid; e < end; e += 256)
    atomicAdd(&hist[dst[e] >> BKT_SHIFT], 1);
  __syncthreads();
  if (tid < nbkt) {
    int c = hist[tid];
    bbase[tid] = c > 0 ? atomicAdd(&bkt_cursor[tid], c) : 0;
    hist[tid] = 0;  // reuse as intra-block cursor
  }
  __syncthreads();
  for (int e = base + tid; e < end; e += 256) {
    int d = dst[e];
    int b = d >> BKT_SHIFT;
    int off = atomicAdd(&hist[b], 1);
    ebuf[bbase[b] + off] = make_int2(src[e], d);
  }
}

// P2: place edges into padded CSR as {src, w}; fill pad slots with {node, 0}
__global__ __launch_bounds__(256) void bucket_place_kernel(const int2* __restrict__ ebuf,
                                                           const int* __restrict__ bkt_start,
                                                           const int* __restrict__ row_start,
                                                           const float* __restrict__ dinv,
                                                           int2* __restrict__ csr,
                                                           int N, int nbkt) {
  __shared__ float sdinv[BKT_SIZE];
  __shared__ int srs[BKT_SIZE];
  __shared__ int scur[BKT_SIZE];
  const int b = blockIdx.x;
  const int tid = threadIdx.x;
  const int node0 = b << BKT_SHIFT;
  const int nloc = min(BKT_SIZE, N - node0);
  for (int l = tid; l < nloc; l += 256) {
    sdinv[l] = dinv[node0 + l];
    srs[l] = row_start[node0 + l];
    scur[l] = 0;
  }
  __syncthreads();
  const int ebeg = bkt_start[b], eend = bkt_start[b + 1];
  for (int e = ebeg + tid; e < eend; e += 256) {
    int2 ed = ebuf[e];
    int l = ed.y - node0;
    int pos = atomicAdd(&scur[l], 1);
    float w = sdinv[l] * dinv[ed.x];
    csr[srs[l] + pos] = make_int2(ed.x, __float_as_int(w));
  }
  __syncthreads();
  for (int l = tid; l < nloc; l += 256) {
    int re = (l + 1 < nloc) ? srs[l + 1] : row_start[node0 + nloc];
    int2 pad = make_int2(node0 + l, 0);
    for (int p = srs[l] + scur[l]; p < re; ++p) csr[p] = pad;
  }
}

// ================= fused conversions: x->bf16, W1->Wt1, W2->Wt2 =================

__global__ __launch_bounds__(256) void prep_kernel(const float4* __restrict__ x4,
                                                   unsigned short* __restrict__ xb, int n4,
                                                   const float* __restrict__ W1,
                                                   unsigned short* __restrict__ Wt1,
                                                   const float* __restrict__ W2,
                                                   unsigned short* __restrict__ Wt2) {
  const int nxblk = (n4 + 255) / 256;
  const int bid = blockIdx.x;
  if (bid < nxblk) {
    int i = bid * 256 + threadIdx.x;
    if (i >= n4) return;
    float4 v = x4[i];
    ushort4 o;
    o.x = f2b(v.x); o.y = f2b(v.y); o.z = f2b(v.z); o.w = f2b(v.w);
    *(ushort4*)(xb + (size_t)i * 4) = o;
  } else if (bid < nxblk + 128) {
    // W1[K=128][N=256] -> Wt1[N][K]
    int e = (bid - nxblk) * 256 + threadIdx.x;
    int k = e >> 8, n = e & 255;
    Wt1[(size_t)n * D_IN + k] = f2b(W1[e]);
  } else {
    // W2[K=256][N=128] -> Wt2[N][K]
    int e = (bid - nxblk - 128) * 256 + threadIdx.x;
    int k = e >> 7, n = e & 127;
    Wt2[(size_t)n * HID + k] = f2b(W2[e]);
  }
}

// ================= MFMA bf16 GEMM: H[M][N_COLS] = A[M][K] @ Wt[N_COLS][K]^T =================

template<int N_COLS, int K, bool BIAS_RELU>
__global__ __launch_bounds__(256) void mfma_gemm_kernel(const unsigned short* __restrict__ A,
                                                        const unsigned short* __restrict__ Wt,
                                                        const float* __restrict__ bias,
                                                        unsigned short* __restrict__ H, int M) {
  const int tid = threadIdx.x;
  const int wave = tid >> 6;
  const int lane = tid & 63;
  const int quad = lane >> 4;
  const int l16 = lane & 15;
  const int row0 = blockIdx.x * 64 + wave * 16;
  const int col0 = blockIdx.y * 64;

  int arow = row0 + l16;
  if (arow >= M) arow = M - 1;  // tail: loads clamped, stores guarded
  const short8* ap = (const short8*)(A + (size_t)arow * K + quad * 8);
  const short8* bp = (const short8*)(Wt + (size_t)(col0 + l16) * K + quad * 8);
  constexpr int BSTEP = 2 * K;  // 16 rows of Wt in short8 units

  floatx4 acc0 = {0.f, 0.f, 0.f, 0.f}, acc1 = acc0, acc2 = acc0, acc3 = acc0;
#pragma unroll
  for (int kt = 0; kt < K / 32; ++kt) {
    short8 a  = ap[kt * 4];
    short8 b0 = bp[kt * 4];
    short8 b1 = bp[kt * 4 + BSTEP];
    short8 b2 = bp[kt * 4 + 2 * BSTEP];
    short8 b3 = bp[kt * 4 + 3 * BSTEP];
    acc0 = __builtin_amdgcn_mfma_f32_16x16x32_bf16(a, b0, acc0, 0, 0, 0);
    acc1 = __builtin_amdgcn_mfma_f32_16x16x32_bf16(a, b1, acc1, 0, 0, 0);
    acc2 = __builtin_amdgcn_mfma_f32_16x16x32_bf16(a, b2, acc2, 0, 0, 0);
    acc3 = __builtin_amdgcn_mfma_f32_16x16x32_bf16(a, b3, acc3, 0, 0, 0);
  }

  floatx4 accs[4] = {acc0, acc1, acc2, acc3};
#pragma unroll
  for (int t = 0; t < 4; ++t) {
    const int col = col0 + t * 16 + l16;
    const float bv = BIAS_RELU ? bias[col] : 0.f;
#pragma unroll
    for (int r = 0; r < 4; ++r) {
      const int row = row0 + quad * 4 + r;
      if (row < M) {
        float v = accs[t][r];
        if (BIAS_RELU) { v += bv; v = v > 0.f ? v : 0.f; }
        H[(size_t)row * N_COLS + col] = f2b(v);
      }
    }
  }
}

// ================= CSR aggregation (D=128 bf16), unroll-8, padded rows =================
// 16 lanes/node (uint4 = 8 bf16 per gather), 16 nodes/block. Rows are multiples of 8
// slots, 64B-aligned -> int4 loads of interleaved {src,w}; pad slots have w=0.

template<bool SKIP_BIAS>
__global__ __launch_bounds__(256) void agg_kernel(const uint4* __restrict__ Hq,
                                                  const int* __restrict__ row_start,
                                                  const int2* __restrict__ csr,
                                                  const float* __restrict__ dinv,
                                                  const float* __restrict__ skip,
                                                  const float* __restrict__ bias,
                                                  void* __restrict__ OUT, int n) {
  const int lane = threadIdx.x & 15;
  const int node = blockIdx.x * 16 + (threadIdx.x >> 4);
  if (node >= n) return;

  const float dv = dinv[node];
  float acc[8];
  {
    uint4 sv = Hq[(size_t)node * 16 + lane];
    float f[8];
    unpack8(sv, f);
    const float ws = dv * dv;
#pragma unroll
    for (int d = 0; d < 8; ++d) acc[d] = f[d] * ws;
  }

  int j = row_start[node];
  const int end = row_start[node + 1];
  for (; j < end; j += 8) {
    int4 p0 = *(const int4*)(csr + j);
    int4 p1 = *(const int4*)(csr + j + 2);
    int4 p2 = *(const int4*)(csr + j + 4);
    int4 p3 = *(const int4*)(csr + j + 6);
    uint4 v0 = Hq[(size_t)p0.x * 16 + lane];
    uint4 v1 = Hq[(size_t)p0.z * 16 + lane];
    uint4 v2 = Hq[(size_t)p1.x * 16 + lane];
    uint4 v3 = Hq[(size_t)p1.z * 16 + lane];
    uint4 v4 = Hq[(size_t)p2.x * 16 + lane];
    uint4 v5 = Hq[(size_t)p2.z * 16 + lane];
    uint4 v6 = Hq[(size_t)p3.x * 16 + lane];
    uint4 v7 = Hq[(size_t)p3.z * 16 + lane];
    acc_fma(acc, v0, __int_as_float(p0.y));
    acc_fma(acc, v1, __int_as_float(p0.w));
    acc_fma(acc, v2, __int_as_float(p1.y));
    acc_fma(acc, v3, __int_as_float(p1.w));
    acc_fma(acc, v4, __int_as_float(p2.y));
    acc_fma(acc, v5, __int_as_float(p2.w));
    acc_fma(acc, v6, __int_as_float(p3.y));
    acc_fma(acc, v7, __int_as_float(p3.w));
  }

  if (SKIP_BIAS) {
    const float* sp = skip + (size_t)node * 128 + lane * 8;
    const float* bp = bias + lane * 8;
    float4 s0 = *(const float4*)sp, s1 = *(const float4*)(sp + 4);
    float4 b0 = *(const float4*)bp, b1 = *(const float4*)(bp + 4);
    float* op = (float*)OUT + (size_t)node * 128 + lane * 8;
    *(float4*)op = make_float4(acc[0] + s0.x + b0.x, acc[1] + s0.y + b0.y,
                               acc[2] + s0.z + b0.z, acc[3] + s0.w + b0.w);
    *(float4*)(op + 4) = make_float4(acc[4] + s1.x + b1.x, acc[5] + s1.y + b1.y,
                                     acc[6] + s1.z + b1.z, acc[7] + s1.w + b1.w);
  } else {
    uint4 o;
    o.x = (unsigned)f2b(acc[0]) | ((unsigned)f2b(acc[1]) << 16);
    o.y = (unsigned)f2b(acc[2]) | ((unsigned)f2b(acc[3]) << 16);
    o.z = (unsigned)f2b(acc[4]) | ((unsigned)f2b(acc[5]) << 16);
    o.w = (unsigned)f2b(acc[6]) | ((unsigned)f2b(acc[7]) << 16);
    ((uint4*)OUT)[(size_t)node * 16 + lane] = o;
  }
}

// ================= launch =================

extern "C" void kernel_launch(void* const* d_in, const int* in_sizes, int n_in,
                              void* d_out, int out_size, void* d_ws, size_t ws_size,
                              hipStream_t stream) {
  const float* x  = (const float*)d_in[0];
  const int*   ei = (const int*)d_in[1];
  const float* W1 = (const float*)d_in[2];
  const float* b1 = (const float*)d_in[3];
  const float* W2 = (const float*)d_in[4];
  const float* b2 = (const float*)d_in[5];
  float* out = (float*)d_out;

  const int N = in_sizes[0] / D_IN;
  const int E = in_sizes[1] / 2;
  const int* srcA = ei;
  const int* dstA = ei + E;
  const int NBKT = (N + BKT_SIZE - 1) >> BKT_SHIFT;  // 98 for N=50000
  const int NCHUNK = (E + CHUNK - 1) / CHUNK;
  const int NB = (N + 1023) / 1024;                  // 49, <=64

  // ---- workspace (256B aligned) ----
  char* ws = (char*)d_ws;
  size_t off = 0;
  auto alloc = [&](size_t bytes) { void* p = ws + off; off = (off + bytes + 255) & ~(size_t)255; return p; };
  int*            cnt        = (int*)           alloc((size_t)(N + NBKT) * 4);  // bkt_cnt appended
  int*            bkt_cnt    = cnt + N;
  int*            bkt_start  = (int*)           alloc((size_t)(NBKT + 1) * 4);
  int*            bkt_cursor = (int*)           alloc((size_t)NBKT * 4);
  int*            row_start  = (int*)           alloc((size_t)(N + 1) * 4);
  float*          dinv       = (float*)         alloc((size_t)N * 4);
  int*            blksum     = (int*)           alloc((size_t)(NB + 1) * 4);
  int2*           ebuf       = (int2*)          alloc((size_t)E * 8);
  int2*           csr        = (int2*)          alloc(((size_t)E + 8 * (size_t)N) * 8);  // padded
  unsigned short* xb         = (unsigned short*)alloc((size_t)N * D_IN * 2);
  unsigned short* aggx       = (unsigned short*)alloc((size_t)N * D_IN * 2);
  unsigned short* h          = (unsigned short*)alloc((size_t)N * HID * 2);
  unsigned short* tb         = (unsigned short*)alloc((size_t)N * D_IN * 2);
  unsigned short* Wt1        = (unsigned short*)alloc((size_t)D_IN * HID * 2);
  unsigned short* Wt2        = (unsigned short*)alloc((size_t)D_IN * HID * 2);

  // 1) degrees + bucket histogram (one pass over dst)
  hipMemsetAsync(cnt, 0, (size_t)(N + NBKT) * 4, stream);
  cdh_kernel<<<NCHUNK, 256, 0, stream>>>(dstA, cnt, bkt_cnt, E, NBKT);
  // 2) padded row_start scan + dinv; bucket scan
  scanA_kernel<<<NB, 256, 0, stream>>>(cnt, dinv, row_start, blksum, N);
  scan_mid_kernel<<<1, 256, 0, stream>>>(bkt_cnt, bkt_start, bkt_cursor, NBKT, E, blksum, NB);
  scanC_kernel<<<NB, 256, 0, stream>>>(row_start, blksum, N, NB);
  // 3) bin edges, then place into padded CSR with precomputed w
  bin_scatter_kernel<<<NCHUNK, 256, 0, stream>>>(srcA, dstA, bkt_cursor, ebuf, E, NBKT);
  bucket_place_kernel<<<NBKT, 256, 0, stream>>>(ebuf, bkt_start, row_start, dinv, csr, N, NBKT);
  // 4) conversions (x -> bf16, W -> Wt bf16)
  {
    const int n4 = N * D_IN / 4;
    prep_kernel<<<(n4 + 255) / 256 + 256, 256, 0, stream>>>((const float4*)x, xb, n4,
                                                            W1, Wt1, W2, Wt2);
  }
  // 5) aggx = Â x
  agg_kernel<false><<<(N + 15) / 16, 256, 0, stream>>>((const uint4*)xb, row_start, csr,
                                                       dinv, nullptr, nullptr, aggx, N);
  // 6) h = relu(aggx @ W1 + b1)
  {
    dim3 g((N + 63) / 64, HID / 64);
    mfma_gemm_kernel<HID, D_IN, true><<<g, 256, 0, stream>>>(aggx, Wt1, b1, h, N);
  }
  // 7) t = h @ W2
  {
    dim3 g((N + 63) / 64, D_IN / 64);
    mfma_gemm_kernel<D_IN, HID, false><<<g, 256, 0, stream>>>(h, Wt2, nullptr, tb, N);
  }
  // 8) out = Â t + x + b2
  agg_kernel<true><<<(N + 15) / 16, 256, 0, stream>>>((const uint4*)tb, row_start, csr,
                                                      dinv, x, b2, out, N);
}

// Round 7
// 359.350 us; speedup vs baseline: 1.1435x; 1.1435x over previous
//
#include <hip/hip_runtime.h>

#define D_IN 128
#define HID 256
#define BKT_SHIFT 9
#define BKT_SIZE 512     // nodes per bucket (N<=65536 -> nbkt<=128)
#define CHUNK 4096       // edges per block in binning kernels

typedef __attribute__((ext_vector_type(8))) short short8;   // 8 bf16 MFMA A/B frag
typedef __attribute__((ext_vector_type(4))) float floatx4;  // MFMA C/D frag

// fp32 -> bf16 (RNE), branch-free; inputs finite
static __device__ __forceinline__ unsigned short f2b(float f) {
  unsigned u = __float_as_uint(f);
  unsigned r = (u + 0x7fffu + ((u >> 16) & 1u)) >> 16;
  return (unsigned short)r;
}

static __device__ __forceinline__ void unpack8(uint4 v, float* f) {
  f[0] = __uint_as_float(v.x << 16); f[1] = __uint_as_float(v.x & 0xffff0000u);
  f[2] = __uint_as_float(v.y << 16); f[3] = __uint_as_float(v.y & 0xffff0000u);
  f[4] = __uint_as_float(v.z << 16); f[5] = __uint_as_float(v.z & 0xffff0000u);
  f[6] = __uint_as_float(v.w << 16); f[7] = __uint_as_float(v.w & 0xffff0000u);
}

static __device__ __forceinline__ void acc_fma(float* acc, uint4 v, float w) {
  float g[8];
  unpack8(v, g);
#pragma unroll
  for (int d = 0; d < 8; ++d) acc[d] = fmaf(g[d], w, acc[d]);
}

// ================= CSR build =================

// P1a: bucket histogram (LDS-staged; NO per-node global atomics)
__global__ __launch_bounds__(256) void bin_hist_kernel(const int* __restrict__ dst,
                                                       int* __restrict__ bkt_cnt,
                                                       int E, int nbkt) {
  __shared__ int hist[128];
  const int tid = threadIdx.x;
  if (tid < nbkt) hist[tid] = 0;
  __syncthreads();
  const int base = blockIdx.x * CHUNK;
  const int end = min(base + CHUNK, E);
  for (int e = base + tid; e < end; e += 256)
    atomicAdd(&hist[dst[e] >> BKT_SHIFT], 1);
  __syncthreads();
  if (tid < nbkt && hist[tid] > 0) atomicAdd(&bkt_cnt[tid], hist[tid]);
}

// P1b: exclusive scan of bucket counts (nbkt <= 128); init cursors
__global__ __launch_bounds__(128) void bkt_scan_kernel(const int* __restrict__ bkt_cnt,
                                                       int* __restrict__ bkt_start,
                                                       int* __restrict__ bkt_cursor,
                                                       int nbkt, int E) {
  __shared__ int w0tot;
  const int tid = threadIdx.x;
  const int lane = tid & 63, wid = tid >> 6;
  int v = (tid < nbkt) ? bkt_cnt[tid] : 0;
  int incl = v;
#pragma unroll
  for (int off = 1; off < 64; off <<= 1) {
    int t = __shfl_up(incl, off);
    if (lane >= off) incl += t;
  }
  if (wid == 0 && lane == 63) w0tot = incl;
  __syncthreads();
  int ex = incl - v + (wid ? w0tot : 0);
  if (tid < nbkt) { bkt_start[tid] = ex; bkt_cursor[tid] = ex; }
  if (tid == 0) bkt_start[nbkt] = E;
}

// P1c: bin edges into bucket-contiguous runs of ebuf
__global__ __launch_bounds__(256) void bin_scatter_kernel(const int* __restrict__ src,
                                                          const int* __restrict__ dst,
                                                          int* __restrict__ bkt_cursor,
                                                          int2* __restrict__ ebuf,
                                                          int E, int nbkt) {
  __shared__ int hist[128];
  __shared__ int bbase[128];
  const int tid = threadIdx.x;
  if (tid < nbkt) hist[tid] = 0;
  __syncthreads();
  const int base = blockIdx.x * CHUNK;
  const int end = min(base + CHUNK, E);
  for (int e = base + tid; e < end; e += 256)
    atomicAdd(&hist[dst[e] >> BKT_SHIFT], 1);
  __syncthreads();
  if (tid < nbkt) {
    int c = hist[tid];
    bbase[tid] = c > 0 ? atomicAdd(&bkt_cursor[tid], c) : 0;
    hist[tid] = 0;  // reuse as intra-block cursor
  }
  __syncthreads();
  for (int e = base + tid; e < end; e += 256) {
    int d = dst[e];
    int b = d >> BKT_SHIFT;
    int off = atomicAdd(&hist[b], 1);
    ebuf[bbase[b] + off] = make_int2(src[e], d);
  }
}

// P2a: per-bucket degree histogram (LDS) -> dinv, padded-local row offsets, bucket padded total
__global__ __launch_bounds__(256) void bucket_degree_kernel(const int2* __restrict__ ebuf,
                                                            const int* __restrict__ bkt_start,
                                                            float* __restrict__ dinv,
                                                            int* __restrict__ row_local,
                                                            int* __restrict__ pbkt,
                                                            int N) {
  __shared__ int hist[BKT_SIZE];
  __shared__ int wsums[4];
  const int b = blockIdx.x;
  const int tid = threadIdx.x;
  const int node0 = b << BKT_SHIFT;
  const int nloc = min(BKT_SIZE, N - node0);
  const int ebeg = bkt_start[b], eend = bkt_start[b + 1];

  hist[tid] = 0; hist[tid + 256] = 0;
  __syncthreads();
  for (int e = ebeg + tid; e < eend; e += 256)
    atomicAdd(&hist[ebuf[e].y - node0], 1);
  __syncthreads();

  // padded (multiple-of-8) 512-wide exclusive scan, 2 elems/thread
  const int h0 = hist[2 * tid], h1 = hist[2 * tid + 1];
  const int p0 = (h0 + 7) & ~7, p1 = (h1 + 7) & ~7;
  const int s = p0 + p1;
  const int lane = tid & 63, wid = tid >> 6;
  int incl = s;
#pragma unroll
  for (int off = 1; off < 64; off <<= 1) {
    int t = __shfl_up(incl, off);
    if (lane >= off) incl += t;
  }
  if (lane == 63) wsums[wid] = incl;
  __syncthreads();
  int wex = 0;
  for (int w = 0; w < wid; ++w) wex += wsums[w];
  const int ex = wex + incl - s;
  if (2 * tid < nloc) {
    row_local[node0 + 2 * tid] = ex;
    dinv[node0 + 2 * tid] = rsqrtf((float)(h0 + 1));
  }
  if (2 * tid + 1 < nloc) {
    row_local[node0 + 2 * tid + 1] = ex + p0;
    dinv[node0 + 2 * tid + 1] = rsqrtf((float)(h1 + 1));
  }
  if (tid == 255) pbkt[b] = wex + incl;  // bucket padded total
}

// P2b: scan bucket padded totals (nbkt <= 128) -> pbase; pbase[nbkt] = grand total
__global__ __launch_bounds__(128) void pbkt_scan_kernel(int* __restrict__ pbkt,
                                                        int* __restrict__ pbase, int nbkt) {
  __shared__ int w0tot;
  const int tid = threadIdx.x;
  const int lane = tid & 63, wid = tid >> 6;
  int v = (tid < nbkt) ? pbkt[tid] : 0;
  int incl = v;
#pragma unroll
  for (int off = 1; off < 64; off <<= 1) {
    int t = __shfl_up(incl, off);
    if (lane >= off) incl += t;
  }
  if (wid == 0 && lane == 63) w0tot = incl;
  __syncthreads();
  int tot = (wid ? w0tot : 0) + incl;
  if (tid < nbkt) pbase[tid] = tot - v;   // exclusive
  if (tid == nbkt - 1) pbase[nbkt] = tot; // grand total
}

// P2c: finalize row_start; place edges {src, w}; fill pad slots {node, 0}
__global__ __launch_bounds__(256) void bucket_place_kernel(const int2* __restrict__ ebuf,
                                                           const int* __restrict__ bkt_start,
                                                           const int* __restrict__ row_local,
                                                           const int* __restrict__ pbase,
                                                           const float* __restrict__ dinv,
                                                           int* __restrict__ row_start,
                                                           int2* __restrict__ csr,
                                                           int N, int nbkt) {
  __shared__ float sdinv[BKT_SIZE];
  __shared__ int srs[BKT_SIZE];
  __shared__ int scur[BKT_SIZE];
  const int b = blockIdx.x;
  const int tid = threadIdx.x;
  const int node0 = b << BKT_SHIFT;
  const int nloc = min(BKT_SIZE, N - node0);
  const int base = pbase[b];
  for (int l = tid; l < nloc; l += 256) {
    int rs = base + row_local[node0 + l];
    srs[l] = rs;
    row_start[node0 + l] = rs;
    sdinv[l] = dinv[node0 + l];
    scur[l] = 0;
  }
  if (b == 0 && tid == 0) row_start[N] = pbase[nbkt];
  __syncthreads();
  const int ebeg = bkt_start[b], eend = bkt_start[b + 1];
  for (int e = ebeg + tid; e < eend; e += 256) {
    int2 ed = ebuf[e];
    int l = ed.y - node0;
    int pos = atomicAdd(&scur[l], 1);
    float w = sdinv[l] * dinv[ed.x];
    csr[srs[l] + pos] = make_int2(ed.x, __float_as_int(w));
  }
  __syncthreads();
  const int bend = pbase[b + 1 <= nbkt ? b + 1 : nbkt];
  for (int l = tid; l < nloc; l += 256) {
    int re = (l + 1 < nloc) ? srs[l + 1] : bend;
    int2 pad = make_int2(node0 + l, 0);
    for (int p = srs[l] + scur[l]; p < re; ++p) csr[p] = pad;
  }
}

// ================= fused conversions: x->bf16, W1->Wt1, W2->Wt2 =================

__global__ __launch_bounds__(256) void prep_kernel(const float4* __restrict__ x4,
                                                   unsigned short* __restrict__ xb, int n4,
                                                   const float* __restrict__ W1,
                                                   unsigned short* __restrict__ Wt1,
                                                   const float* __restrict__ W2,
                                                   unsigned short* __restrict__ Wt2) {
  const int nxblk = (n4 + 255) / 256;
  const int bid = blockIdx.x;
  if (bid < nxblk) {
    int i = bid * 256 + threadIdx.x;
    if (i >= n4) return;
    float4 v = x4[i];
    ushort4 o;
    o.x = f2b(v.x); o.y = f2b(v.y); o.z = f2b(v.z); o.w = f2b(v.w);
    *(ushort4*)(xb + (size_t)i * 4) = o;
  } else if (bid < nxblk + 128) {
    // W1[K=128][N=256] -> Wt1[N][K]
    int e = (bid - nxblk) * 256 + threadIdx.x;
    int k = e >> 8, n = e & 255;
    Wt1[(size_t)n * D_IN + k] = f2b(W1[e]);
  } else {
    // W2[K=256][N=128] -> Wt2[N][K]
    int e = (bid - nxblk - 128) * 256 + threadIdx.x;
    int k = e >> 7, n = e & 127;
    Wt2[(size_t)n * HID + k] = f2b(W2[e]);
  }
}

// ================= MFMA bf16 GEMM: H[M][N_COLS] = A[M][K] @ Wt[N_COLS][K]^T =================

template<int N_COLS, int K, bool BIAS_RELU>
__global__ __launch_bounds__(256) void mfma_gemm_kernel(const unsigned short* __restrict__ A,
                                                        const unsigned short* __restrict__ Wt,
                                                        const float* __restrict__ bias,
                                                        unsigned short* __restrict__ H, int M) {
  const int tid = threadIdx.x;
  const int wave = tid >> 6;
  const int lane = tid & 63;
  const int quad = lane >> 4;
  const int l16 = lane & 15;
  const int row0 = blockIdx.x * 64 + wave * 16;
  const int col0 = blockIdx.y * 64;

  int arow = row0 + l16;
  if (arow >= M) arow = M - 1;  // tail: loads clamped, stores guarded
  const short8* ap = (const short8*)(A + (size_t)arow * K + quad * 8);
  const short8* bp = (const short8*)(Wt + (size_t)(col0 + l16) * K + quad * 8);
  constexpr int BSTEP = 2 * K;  // 16 rows of Wt in short8 units

  floatx4 acc0 = {0.f, 0.f, 0.f, 0.f}, acc1 = acc0, acc2 = acc0, acc3 = acc0;
#pragma unroll
  for (int kt = 0; kt < K / 32; ++kt) {
    short8 a  = ap[kt * 4];
    short8 b0 = bp[kt * 4];
    short8 b1 = bp[kt * 4 + BSTEP];
    short8 b2 = bp[kt * 4 + 2 * BSTEP];
    short8 b3 = bp[kt * 4 + 3 * BSTEP];
    acc0 = __builtin_amdgcn_mfma_f32_16x16x32_bf16(a, b0, acc0, 0, 0, 0);
    acc1 = __builtin_amdgcn_mfma_f32_16x16x32_bf16(a, b1, acc1, 0, 0, 0);
    acc2 = __builtin_amdgcn_mfma_f32_16x16x32_bf16(a, b2, acc2, 0, 0, 0);
    acc3 = __builtin_amdgcn_mfma_f32_16x16x32_bf16(a, b3, acc3, 0, 0, 0);
  }

  floatx4 accs[4] = {acc0, acc1, acc2, acc3};
#pragma unroll
  for (int t = 0; t < 4; ++t) {
    const int col = col0 + t * 16 + l16;
    const float bv = BIAS_RELU ? bias[col] : 0.f;
#pragma unroll
    for (int r = 0; r < 4; ++r) {
      const int row = row0 + quad * 4 + r;
      if (row < M) {
        float v = accs[t][r];
        if (BIAS_RELU) { v += bv; v = v > 0.f ? v : 0.f; }
        H[(size_t)row * N_COLS + col] = f2b(v);
      }
    }
  }
}

// ================= CSR aggregation (D=128 bf16), unroll-8, padded rows =================
// 16 lanes/node (uint4 = 8 bf16 per gather), 16 nodes/block. Rows are multiples of 8
// slots, 64B-aligned -> int4 loads of interleaved {src,w}; pad slots have w=0.

template<bool SKIP_BIAS>
__global__ __launch_bounds__(256) void agg_kernel(const uint4* __restrict__ Hq,
                                                  const int* __restrict__ row_start,
                                                  const int2* __restrict__ csr,
                                                  const float* __restrict__ dinv,
                                                  const float* __restrict__ skip,
                                                  const float* __restrict__ bias,
                                                  void* __restrict__ OUT, int n) {
  const int lane = threadIdx.x & 15;
  const int node = blockIdx.x * 16 + (threadIdx.x >> 4);
  if (node >= n) return;

  const float dv = dinv[node];
  float acc[8];
  {
    uint4 sv = Hq[(size_t)node * 16 + lane];
    float f[8];
    unpack8(sv, f);
    const float ws = dv * dv;
#pragma unroll
    for (int d = 0; d < 8; ++d) acc[d] = f[d] * ws;
  }

  int j = row_start[node];
  const int end = row_start[node + 1];
  for (; j < end; j += 8) {
    int4 p0 = *(const int4*)(csr + j);
    int4 p1 = *(const int4*)(csr + j + 2);
    int4 p2 = *(const int4*)(csr + j + 4);
    int4 p3 = *(const int4*)(csr + j + 6);
    uint4 v0 = Hq[(size_t)p0.x * 16 + lane];
    uint4 v1 = Hq[(size_t)p0.z * 16 + lane];
    uint4 v2 = Hq[(size_t)p1.x * 16 + lane];
    uint4 v3 = Hq[(size_t)p1.z * 16 + lane];
    uint4 v4 = Hq[(size_t)p2.x * 16 + lane];
    uint4 v5 = Hq[(size_t)p2.z * 16 + lane];
    uint4 v6 = Hq[(size_t)p3.x * 16 + lane];
    uint4 v7 = Hq[(size_t)p3.z * 16 + lane];
    acc_fma(acc, v0, __int_as_float(p0.y));
    acc_fma(acc, v1, __int_as_float(p0.w));
    acc_fma(acc, v2, __int_as_float(p1.y));
    acc_fma(acc, v3, __int_as_float(p1.w));
    acc_fma(acc, v4, __int_as_float(p2.y));
    acc_fma(acc, v5, __int_as_float(p2.w));
    acc_fma(acc, v6, __int_as_float(p3.y));
    acc_fma(acc, v7, __int_as_float(p3.w));
  }

  if (SKIP_BIAS) {
    const float* sp = skip + (size_t)node * 128 + lane * 8;
    const float* bp = bias + lane * 8;
    float4 s0 = *(const float4*)sp, s1 = *(const float4*)(sp + 4);
    float4 b0 = *(const float4*)bp, b1 = *(const float4*)(bp + 4);
    float* op = (float*)OUT + (size_t)node * 128 + lane * 8;
    *(float4*)op = make_float4(acc[0] + s0.x + b0.x, acc[1] + s0.y + b0.y,
                               acc[2] + s0.z + b0.z, acc[3] + s0.w + b0.w);
    *(float4*)(op + 4) = make_float4(acc[4] + s1.x + b1.x, acc[5] + s1.y + b1.y,
                                     acc[6] + s1.z + b1.z, acc[7] + s1.w + b1.w);
  } else {
    uint4 o;
    o.x = (unsigned)f2b(acc[0]) | ((unsigned)f2b(acc[1]) << 16);
    o.y = (unsigned)f2b(acc[2]) | ((unsigned)f2b(acc[3]) << 16);
    o.z = (unsigned)f2b(acc[4]) | ((unsigned)f2b(acc[5]) << 16);
    o.w = (unsigned)f2b(acc[6]) | ((unsigned)f2b(acc[7]) << 16);
    ((uint4*)OUT)[(size_t)node * 16 + lane] = o;
  }
}

// ================= launch =================

extern "C" void kernel_launch(void* const* d_in, const int* in_sizes, int n_in,
                              void* d_out, int out_size, void* d_ws, size_t ws_size,
                              hipStream_t stream) {
  const float* x  = (const float*)d_in[0];
  const int*   ei = (const int*)d_in[1];
  const float* W1 = (const float*)d_in[2];
  const float* b1 = (const float*)d_in[3];
  const float* W2 = (const float*)d_in[4];
  const float* b2 = (const float*)d_in[5];
  float* out = (float*)d_out;

  const int N = in_sizes[0] / D_IN;
  const int E = in_sizes[1] / 2;
  const int* srcA = ei;
  const int* dstA = ei + E;
  const int NBKT = (N + BKT_SIZE - 1) >> BKT_SHIFT;  // 98 for N=50000 (<=128)
  const int NCHUNK = (E + CHUNK - 1) / CHUNK;        // 391

  // ---- workspace (256B aligned) ----
  char* ws = (char*)d_ws;
  size_t off = 0;
  auto alloc = [&](size_t bytes) { void* p = ws + off; off = (off + bytes + 255) & ~(size_t)255; return p; };
  int*            bkt_cnt    = (int*)           alloc((size_t)NBKT * 4);
  int*            bkt_start  = (int*)           alloc((size_t)(NBKT + 1) * 4);
  int*            bkt_cursor = (int*)           alloc((size_t)NBKT * 4);
  int*            pbkt       = (int*)           alloc((size_t)NBKT * 4);
  int*            pbase      = (int*)           alloc((size_t)(NBKT + 1) * 4);
  int*            row_local  = (int*)           alloc((size_t)N * 4);
  int*            row_start  = (int*)           alloc((size_t)(N + 1) * 4);
  float*          dinv       = (float*)         alloc((size_t)N * 4);
  int2*           ebuf       = (int2*)          alloc((size_t)E * 8);
  int2*           csr        = (int2*)          alloc(((size_t)E + 8 * (size_t)N) * 8);  // padded
  unsigned short* xb         = (unsigned short*)alloc((size_t)N * D_IN * 2);
  unsigned short* aggx       = (unsigned short*)alloc((size_t)N * D_IN * 2);
  unsigned short* h          = (unsigned short*)alloc((size_t)N * HID * 2);
  unsigned short* tb         = (unsigned short*)alloc((size_t)N * D_IN * 2);
  unsigned short* Wt1        = (unsigned short*)alloc((size_t)D_IN * HID * 2);
  unsigned short* Wt2        = (unsigned short*)alloc((size_t)D_IN * HID * 2);

  // 1) bucket histogram + scan + binning (no per-node global atomics anywhere)
  hipMemsetAsync(bkt_cnt, 0, (size_t)NBKT * 4, stream);
  bin_hist_kernel<<<NCHUNK, 256, 0, stream>>>(dstA, bkt_cnt, E, NBKT);
  bkt_scan_kernel<<<1, 128, 0, stream>>>(bkt_cnt, bkt_start, bkt_cursor, NBKT, E);
  bin_scatter_kernel<<<NCHUNK, 256, 0, stream>>>(srcA, dstA, bkt_cursor, ebuf, E, NBKT);
  // 2) per-bucket degrees (LDS) -> dinv + padded row offsets; place into padded CSR
  bucket_degree_kernel<<<NBKT, 256, 0, stream>>>(ebuf, bkt_start, dinv, row_local, pbkt, N);
  pbkt_scan_kernel<<<1, 128, 0, stream>>>(pbkt, pbase, NBKT);
  bucket_place_kernel<<<NBKT, 256, 0, stream>>>(ebuf, bkt_start, row_local, pbase, dinv,
                                                row_start, csr, N, NBKT);
  // 3) conversions (x -> bf16, W -> Wt bf16)
  {
    const int n4 = N * D_IN / 4;
    prep_kernel<<<(n4 + 255) / 256 + 256, 256, 0, stream>>>((const float4*)x, xb, n4,
                                                            W1, Wt1, W2, Wt2);
  }
  // 4) aggx = Â x
  agg_kernel<false><<<(N + 15) / 16, 256, 0, stream>>>((const uint4*)xb, row_start, csr,
                                                       dinv, nullptr, nullptr, aggx, N);
  // 5) h = relu(aggx @ W1 + b1)
  {
    dim3 g((N + 63) / 64, HID / 64);
    mfma_gemm_kernel<HID, D_IN, true><<<g, 256, 0, stream>>>(aggx, Wt1, b1, h, N);
  }
  // 6) t = h @ W2
  {
    dim3 g((N + 63) / 64, D_IN / 64);
    mfma_gemm_kernel<D_IN, HID, false><<<g, 256, 0, stream>>>(h, Wt2, nullptr, tb, N);
  }
  // 7) out = Â t + x + b2
  agg_kernel<true><<<(N + 15) / 16, 256, 0, stream>>>((const uint4*)tb, row_start, csr,
                                                      dinv, x, b2, out, N);
}